// Round 12
// baseline (469.553 us; speedup 1.0000x reference)
//
#include <hip/hip_runtime.h>
#include <cfloat>

#define N_NODES 50000
#define N_EDGES 800000
#define N_GRAPHS 64
#define POOL_CHUNK 64
#define DEG_BUCKETS 64
#define SCAN_NB ((N_NODES + 255) / 256)   // 196

// ---------------- CSR build ----------------

__global__ void hist_kernel(const int* __restrict__ dst, int* __restrict__ deg, int n) {
    int i = blockIdx.x * blockDim.x + threadIdx.x;
    if (i < n) atomicAdd(&deg[dst[i]], 1);
}

// ---- parallel exclusive scan of deg -> rowptr/cursor (+ fused degree histogram) ----

__global__ __launch_bounds__(256) void scan_part_kernel(const int* __restrict__ deg,
                                                        int* __restrict__ bsum,
                                                        int* __restrict__ dhist, int n) {
    __shared__ int ws[4];
    __shared__ int lh[DEG_BUCKETS];
    int t = threadIdx.x;
    if (t < DEG_BUCKETS) lh[t] = 0;
    __syncthreads();
    int i = blockIdx.x * 256 + t;
    int v = (i < n) ? deg[i] : 0;
    if (i < n) {
        int d = (v > DEG_BUCKETS - 1) ? DEG_BUCKETS - 1 : v;
        atomicAdd(&lh[d], 1);
    }
    int s = v;
    for (int m = 32; m >= 1; m >>= 1) s += __shfl_xor(s, m, 64);
    if ((t & 63) == 0) ws[t >> 6] = s;
    __syncthreads();
    if (t == 0) bsum[blockIdx.x] = ws[0] + ws[1] + ws[2] + ws[3];
    if (t < DEG_BUCKETS && lh[t]) atomicAdd(&dhist[t], lh[t]);
}

// block-count scan + degree-bucket scan fused (both tiny, single block)
__global__ __launch_bounds__(256) void scan_top_kernel(const int* __restrict__ bsum,
                                                       int* __restrict__ bbase,
                                                       const int* __restrict__ dhist,
                                                       int* __restrict__ dcur) {
    __shared__ int sm[256];
    int t = threadIdx.x;
    int v = (t < SCAN_NB) ? bsum[t] : 0;
    sm[t] = v;
    __syncthreads();
    for (int off = 1; off < 256; off <<= 1) {
        int x = (t >= off) ? sm[t - off] : 0;
        __syncthreads();
        sm[t] += x;
        __syncthreads();
    }
    bbase[t] = sm[t] - v;                       // exclusive
    if (t == 255) bbase[256] = sm[255];         // total
    if (t < 64) {
        int dv = dhist[t];
        int incl = dv;
        for (int off = 1; off < 64; off <<= 1) {
            int x = __shfl_up(incl, off, 64);
            if (t >= off) incl += x;
        }
        dcur[t] = incl - dv;                    // exclusive
    }
}

// fused: rowptr/cursor write + degree-bucket permutation scatter
__global__ __launch_bounds__(256) void scan_write_perm_kernel(const int* __restrict__ deg,
        const int* __restrict__ bbase, int* __restrict__ rowptr,
        int* __restrict__ cursor, int* __restrict__ dcur,
        int* __restrict__ perm, int n) {
    __shared__ int sm[256];
    __shared__ int lh[DEG_BUCKETS];
    __shared__ int lbase[DEG_BUCKETS];
    int t = threadIdx.x;
    int b = blockIdx.x;
    int i = b * 256 + t;
    int v = (i < n) ? deg[i] : 0;
    sm[t] = v;
    if (t < DEG_BUCKETS) lh[t] = 0;
    __syncthreads();
    int d = 0, loc = 0;
    bool valid = (i < n);
    if (valid) {
        d = (v > DEG_BUCKETS - 1) ? DEG_BUCKETS - 1 : v;
        loc = atomicAdd(&lh[d], 1);             // local rank within (block, bin)
    }
    for (int off = 1; off < 256; off <<= 1) {
        int x = (t >= off) ? sm[t - off] : 0;
        __syncthreads();
        sm[t] += x;
        __syncthreads();
    }
    if (t < DEG_BUCKETS)
        lbase[t] = lh[t] ? atomicAdd(&dcur[t], lh[t]) : 0;
    if (valid) {
        int e = bbase[b] + sm[t] - v;
        rowptr[i] = e;
        cursor[i] = e;
    }
    if (b == 0 && t == 0) rowptr[n] = bbase[256];
    __syncthreads();
    if (valid) perm[lbase[d] + loc] = i;
}

__global__ void scatter_kernel(const int* __restrict__ src, const int* __restrict__ dst,
                               int* __restrict__ cursor, int* __restrict__ csrc, int n) {
    int i = blockIdx.x * blockDim.x + threadIdx.x;
    if (i < n) {
        int d = dst[i];
        int p = atomicAdd(&cursor[d], 1);
        csrc[p] = src[i];
    }
}

// ---------------- fused dual GEMM: xl = h@Wl, xr = h@Wr ----------------
// One block per row-tile (non-persistent — persistent variant was pathological, r8).

template<int DIN, int DOUT, int TR, int RPT>
__global__ __launch_bounds__(256) void gemm2_kernel(const float* __restrict__ h,
        const float* __restrict__ Wl, const float* __restrict__ Wr,
        float* __restrict__ xl, float* __restrict__ xr, int n) {
    constexpr int CG = (2 * DOUT) / 4;
    constexpr int RG = 256 / CG;
    static_assert(RG * RPT == TR, "tile rows mismatch");
    static_assert(RPT % 4 == 0, "RPT multiple of 4");
    constexpr int TRP = TR + 4;
    __shared__ float sW[2 * DIN * DOUT];
    __shared__ float sX[DIN * TRP];
    int tid = threadIdx.x;
    for (int i = tid; i < DIN * DOUT; i += 256) {
        sW[i] = Wl[i];
        sW[DIN * DOUT + i] = Wr[i];
    }
    int r0 = blockIdx.x * TR;
    for (int i = tid; i < TR * DIN; i += 256) {
        int row = i / DIN, k = i % DIN;
        float v = (r0 + row < n) ? h[(r0 + row) * DIN + k] : 0.f;
        sX[k * TRP + row] = v;
    }
    __syncthreads();

    int cg = tid % CG, rg = tid / CG;
    int c = cg * 4;
    int sel = (c >= DOUT) ? 1 : 0;
    int cc = c - sel * DOUT;
    const float* wp = sW + sel * DIN * DOUT + cc;
    const float* xp = sX + rg * RPT;

    float acc[RPT][4] = {};
#pragma unroll 4
    for (int k = 0; k < DIN; ++k) {
        float4 wv = *(const float4*)(wp + k * DOUT);
        float wa[4] = {wv.x, wv.y, wv.z, wv.w};
        float xa[RPT];
#pragma unroll
        for (int rr = 0; rr < RPT; rr += 4) {
            float4 xv = *(const float4*)(xp + k * TRP + rr);
            xa[rr + 0] = xv.x; xa[rr + 1] = xv.y; xa[rr + 2] = xv.z; xa[rr + 3] = xv.w;
        }
#pragma unroll
        for (int r = 0; r < RPT; ++r)
#pragma unroll
            for (int q = 0; q < 4; ++q)
                acc[r][q] += xa[r] * wa[q];
    }

    float* obase = sel ? xr : xl;
#pragma unroll
    for (int r = 0; r < RPT; ++r) {
        int row = r0 + rg * RPT + r;
        if (row < n) {
            float4 o = make_float4(acc[r][0], acc[r][1], acc[r][2], acc[r][3]);
            *(float4*)(obase + row * DOUT + cc) = o;
        }
    }
}

// Split-W variant: each block computes ONE of {xl, xr} (sel = blockIdx&1).
template<int DIN, int DOUT, int TR, int RPT>
__global__ __launch_bounds__(256) void gemm1w_kernel(const float* __restrict__ h,
        const float* __restrict__ Wl, const float* __restrict__ Wr,
        float* __restrict__ xl, float* __restrict__ xr, int n) {
    constexpr int CG = DOUT / 4;
    constexpr int RG = 256 / CG;
    static_assert(RG * RPT == TR, "tile rows mismatch");
    static_assert(RPT % 4 == 0, "RPT multiple of 4");
    constexpr int TRP = TR + 4;
    __shared__ float sW[DIN * DOUT];
    __shared__ float sX[DIN * TRP];
    int tid = threadIdx.x;
    int sel = blockIdx.x & 1;
    const float* W = sel ? Wr : Wl;
    for (int i = tid; i < DIN * DOUT; i += 256) sW[i] = W[i];
    int r0 = (blockIdx.x >> 1) * TR;
    for (int i = tid; i < TR * DIN; i += 256) {
        int row = i / DIN, k = i % DIN;
        float v = (r0 + row < n) ? h[(r0 + row) * DIN + k] : 0.f;
        sX[k * TRP + row] = v;
    }
    __syncthreads();

    int cg = tid % CG, rg = tid / CG;
    int cc = cg * 4;
    const float* wp = sW + cc;
    const float* xp = sX + rg * RPT;

    float acc[RPT][4] = {};
#pragma unroll 4
    for (int k = 0; k < DIN; ++k) {
        float4 wv = *(const float4*)(wp + k * DOUT);
        float wa[4] = {wv.x, wv.y, wv.z, wv.w};
        float xa[RPT];
#pragma unroll
        for (int rr = 0; rr < RPT; rr += 4) {
            float4 xv = *(const float4*)(xp + k * TRP + rr);
            xa[rr + 0] = xv.x; xa[rr + 1] = xv.y; xa[rr + 2] = xv.z; xa[rr + 3] = xv.w;
        }
#pragma unroll
        for (int r = 0; r < RPT; ++r)
#pragma unroll
            for (int q = 0; q < 4; ++q)
                acc[r][q] += xa[r] * wa[q];
    }

    float* obase = sel ? xr : xl;
#pragma unroll
    for (int r = 0; r < RPT; ++r) {
        int row = r0 + rg * RPT + r;
        if (row < n) {
            float4 o = make_float4(acc[r][0], acc[r][1], acc[r][2], acc[r][3]);
            *(float4*)(obase + row * DOUT + cc) = o;
        }
    }
}

// ---------------- fused per-node GATv2 softmax-aggregate ----------------
// GROUPS=2 sub-groups per node: edge list split between two independent lane
// groups (valid because no-max-sub softmax sums are associative), merged with
// 5 end-of-loop shuffles. Halves the serial U-batch chain per node. LPT order.

template<int DOUT, bool LEAKY>
__global__ __launch_bounds__(256) void edge_kernel(
        const float* __restrict__ xl, const float* __restrict__ xr,
        const float* __restrict__ avec, const float* __restrict__ bias,
        const int* __restrict__ rowptr, const int* __restrict__ csrc,
        const int* __restrict__ perm,
        float* __restrict__ out, int n) {
    constexpr int LANES = DOUT / 4;              // 8 / 16 / 32
    constexpr int SPAN = LANES * 2;              // lanes per node (2 sub-groups)
    constexpr int NPW = 64 / SPAN;               // nodes per wave (4 / 2 / 1)
    constexpr int U = 8;
    int wid = (blockIdx.x * blockDim.x + threadIdx.x) >> 6;
    int lane = threadIdx.x & 63;
    int sgroup = lane / SPAN;
    int sub = (lane / LANES) & 1;
    int gl = lane % LANES;
    int gnode = wid * NPW + sgroup;
    if (gnode >= n) return;
    int node = perm[n - 1 - gnode];              // descending degree (LPT)

    constexpr float L2E = 1.44269504f;
    float4 a0 = *(const float4*)(avec + 4 * gl);
    float4 a6, a4;
    a6.x = 0.6f * L2E * a0.x; a6.y = 0.6f * L2E * a0.y;
    a6.z = 0.6f * L2E * a0.z; a6.w = 0.6f * L2E * a0.w;
    a4.x = 0.4f * L2E * a0.x; a4.y = 0.4f * L2E * a0.y;
    a4.z = 0.4f * L2E * a0.z; a4.w = 0.4f * L2E * a0.w;

    int nbase = node * DOUT + 4 * gl;
    float4 xrv = *(const float4*)(xr + nbase);
    const float* xlg = xl + 4 * gl;

    float4 acc = make_float4(0.f, 0.f, 0.f, 0.f);
    float denom = 0.f;
    int e0 = rowptr[node], e1 = rowptr[node + 1];

    for (int p = e0 + sub * U; p < e1; p += 2 * U) {
        int sidx[U];
#pragma unroll
        for (int u = 0; u < U; ++u) {
            int q = p + u;
            sidx[u] = (q < e1) ? csrc[q] : -1;
        }
        float4 xlv[U];
        float part[U];
#pragma unroll
        for (int u = 0; u < U; ++u) {
            int s = (sidx[u] >= 0) ? sidx[u] : 0;
            xlv[u] = *(const float4*)(xlg + s * DOUT);
            float t0 = xlv[u].x + xrv.x;
            float t1 = xlv[u].y + xrv.y;
            float t2 = xlv[u].z + xrv.z;
            float t3 = xlv[u].w + xrv.w;
            float pu = a6.x * t0 + a4.x * fabsf(t0);
            pu += a6.y * t1 + a4.y * fabsf(t1);
            pu += a6.z * t2 + a4.z * fabsf(t2);
            pu += a6.w * t3 + a4.w * fabsf(t3);
            part[u] = pu;
        }
#pragma unroll
        for (int mask = LANES / 2; mask >= 1; mask >>= 1)
#pragma unroll
            for (int u = 0; u < U; ++u)
                part[u] += __shfl_xor(part[u], mask, 64);
#pragma unroll
        for (int u = 0; u < U; ++u) {
            float w = __builtin_exp2f(part[u]);   // v_exp_f32
            w = (sidx[u] >= 0) ? w : 0.f;
            denom += w;
            acc.x += w * xlv[u].x; acc.y += w * xlv[u].y;
            acc.z += w * xlv[u].z; acc.w += w * xlv[u].w;
        }
    }
    // merge the two sub-groups' partial sums (xor at distance LANES)
    denom += __shfl_xor(denom, LANES, 64);
    acc.x += __shfl_xor(acc.x, LANES, 64);
    acc.y += __shfl_xor(acc.y, LANES, 64);
    acc.z += __shfl_xor(acc.z, LANES, 64);
    acc.w += __shfl_xor(acc.w, LANES, 64);

    if (sub == 0) {
        float inv = 1.f / (denom + 1e-16f);
        float4 bv = *(const float4*)(bias + 4 * gl);
        float4 o;
        o.x = acc.x * inv + bv.x; o.y = acc.y * inv + bv.y;
        o.z = acc.z * inv + bv.z; o.w = acc.w * inv + bv.w;
        if (LEAKY) {
            o.x = (o.x > 0.f) ? o.x : 0.01f * o.x;
            o.y = (o.y > 0.f) ? o.y : 0.01f * o.y;
            o.z = (o.z > 0.f) ? o.z : 0.01f * o.z;
            o.w = (o.w > 0.f) ? o.w : 0.01f * o.w;
        }
        *(float4*)(out + nbase) = o;
    }
}

// ---------------- global max pool (node-parallel, atomicMax on encoded uint) ----------------

__device__ __forceinline__ unsigned int enc_f32(float f) {
    unsigned int b = __float_as_uint(f);
    return (b & 0x80000000u) ? ~b : (b | 0x80000000u);
}
__device__ __forceinline__ float dec_f32(unsigned int u) {
    unsigned int b = (u & 0x80000000u) ? (u ^ 0x80000000u) : ~u;
    return __uint_as_float(b);
}

__global__ __launch_bounds__(128) void pool_kernel(const float* __restrict__ h,
        const int* __restrict__ batch, unsigned int* __restrict__ gout, int n) {
    int c0 = blockIdx.x * POOL_CHUNK;
    if (c0 >= n) return;
    int end = c0 + POOL_CHUNK; if (end > n) end = n;
    int d = threadIdx.x;  // 128
    float run = -FLT_MAX;
    int gcur = batch[c0];
    for (int nn = c0; nn < end; ++nn) {
        int g = batch[nn];
        if (g != gcur) {                       // wave-uniform branch
            atomicMax(&gout[gcur * 128 + d], enc_f32(run));
            run = -FLT_MAX;
            gcur = g;
        }
        run = fmaxf(run, h[nn * 128 + d]);
    }
    atomicMax(&gout[gcur * 128 + d], enc_f32(run));
}

// ---------------- MLP head: column x k-split parallel kernels ----------------

__global__ __launch_bounds__(256) void mlp1_kernel(const unsigned int* __restrict__ gpool,
        const float* __restrict__ w1, const float* __restrict__ b1,
        float* __restrict__ act1) {
    __shared__ float A[128];
    int g = blockIdx.x >> 2, chunk = blockIdx.x & 3;
    int t = threadIdx.x;
    if (t < 128) A[t] = dec_f32(gpool[g * 128 + t]);
    __syncthreads();
    int c = chunk * 256 + t;
    float a0 = b1[c], a1 = 0.f;
#pragma unroll 4
    for (int k = 0; k < 128; k += 2) {
        a0 += A[k] * w1[k * 1024 + c];
        a1 += A[k + 1] * w1[(k + 1) * 1024 + c];
    }
    act1[g * 1024 + c] = fmaxf(a0 + a1, 0.f);
}

template<int DIN, int DOUT>
__global__ __launch_bounds__(256) void mlp_mid_kernel(const float* __restrict__ actin,
        const float* __restrict__ w, const float* __restrict__ b,
        float* __restrict__ actout) {
    constexpr int CHUNKS = DOUT / 64;
    constexpr int KQ = DIN / 4;                 // k per split
    __shared__ float A[DIN];
    __shared__ float partial[4][64];
    int g = blockIdx.x / CHUNKS, chunk = blockIdx.x % CHUNKS;
    int t = threadIdx.x;
    for (int i = t; i < DIN; i += 256) A[i] = actin[g * DIN + i];
    __syncthreads();
    int c = chunk * 64 + (t & 63);
    int q = t >> 6;
    const float* wp = w + c + (size_t)q * KQ * DOUT;
    const float* ap = A + q * KQ;
    float a0 = 0.f, a1 = 0.f;
#pragma unroll 4
    for (int k = 0; k < KQ; k += 2) {
        a0 += ap[k] * wp[k * DOUT];
        a1 += ap[k + 1] * wp[(k + 1) * DOUT];
    }
    partial[q][t & 63] = a0 + a1;
    __syncthreads();
    if (t < 64) {
        float s = partial[0][t] + partial[1][t] + partial[2][t] + partial[3][t] + b[c];
        actout[g * DOUT + chunk * 64 + t] = fmaxf(s, 0.f);
    }
}

__global__ __launch_bounds__(128) void mlp45_kernel(const float* __restrict__ act3,
        const float* __restrict__ w4, const float* __restrict__ b4,
        const float* __restrict__ w5, const float* __restrict__ b5,
        float* __restrict__ out) {
    __shared__ float C[128], D[32];
    int g = blockIdx.x, t = threadIdx.x;
    if (t < 128) C[t] = act3[g * 128 + t];
    __syncthreads();
    if (t < 32) {
        float acc = b4[t];
#pragma unroll 4
        for (int k = 0; k < 128; ++k) acc += C[k] * w4[k * 32 + t];
        D[t] = fmaxf(acc, 0.f);
    }
    __syncthreads();
    if (t < 4) {
        float acc = b5[t];
#pragma unroll
        for (int k = 0; k < 32; ++k) acc += D[k] * w5[k * 4 + t];
        out[g * 4 + t] = acc;
    }
}

// ---------------- host launch ----------------

extern "C" void kernel_launch(void* const* d_in, const int* in_sizes, int n_in,
                              void* d_out, int out_size, void* d_ws, size_t ws_size,
                              hipStream_t stream) {
    const float* x     = (const float*)d_in[0];
    const int*   ei    = (const int*)d_in[1];
    const int*   batch = (const int*)d_in[2];
    const int*   src   = ei;
    const int*   dst   = ei + N_EDGES;
    const float* Wl1 = (const float*)d_in[3];
    const float* Wr1 = (const float*)d_in[4];
    const float* a1  = (const float*)d_in[5];
    const float* b1  = (const float*)d_in[6];
    const float* Wl2 = (const float*)d_in[7];
    const float* Wr2 = (const float*)d_in[8];
    const float* a2  = (const float*)d_in[9];
    const float* b2  = (const float*)d_in[10];
    const float* Wl3 = (const float*)d_in[11];
    const float* Wr3 = (const float*)d_in[12];
    const float* a3  = (const float*)d_in[13];
    const float* b3  = (const float*)d_in[14];
    const float* mw1 = (const float*)d_in[15];
    const float* mb1 = (const float*)d_in[16];
    const float* mw2 = (const float*)d_in[17];
    const float* mb2 = (const float*)d_in[18];
    const float* mw3 = (const float*)d_in[19];
    const float* mb3 = (const float*)d_in[20];
    const float* mw4 = (const float*)d_in[21];
    const float* mb4 = (const float*)d_in[22];
    const float* mw5 = (const float*)d_in[23];
    const float* mb5 = (const float*)d_in[24];

    char* ws = (char*)d_ws;
    size_t off = 0;
    auto alloc = [&](size_t bytes) -> void* {
        void* p = ws + off;
        off = (off + bytes + 255) & ~(size_t)255;
        return p;
    };
    // zero-init region: deg, dhist, pool contiguous -> single memset
    int*   deg    = (int*)alloc(N_NODES * 4);
    int*   dhist  = (int*)alloc(DEG_BUCKETS * 4);
    unsigned int* pool = (unsigned int*)alloc(N_GRAPHS * 128 * 4);
    size_t zero_bytes = off;   // covers deg..pool (0 == encoded -inf for pool)
    int*   rowptr = (int*)alloc((N_NODES + 1) * 4);
    int*   cursor = (int*)alloc(N_NODES * 4);
    int*   csrc   = (int*)alloc(N_EDGES * 4);
    float* xl     = (float*)alloc((size_t)N_NODES * 128 * 4);
    float* xr     = (float*)alloc((size_t)N_NODES * 128 * 4);
    float* hA     = (float*)alloc((size_t)N_NODES * 128 * 4);
    float* hB     = (float*)alloc((size_t)N_NODES * 128 * 4);
    int*   dcur   = (int*)alloc(DEG_BUCKETS * 4);
    int*   perm   = (int*)alloc(N_NODES * 4);
    int*   bsum   = (int*)alloc(SCAN_NB * 4);
    int*   bbase  = (int*)alloc(257 * 4);
    float* act1   = (float*)alloc(N_GRAPHS * 1024 * 4);
    float* act2   = (float*)alloc(N_GRAPHS * 512 * 4);
    float* act3   = (float*)alloc(N_GRAPHS * 128 * 4);

    hipMemsetAsync(deg, 0, zero_bytes, stream);
    hist_kernel<<<(N_EDGES + 255) / 256, 256, 0, stream>>>(dst, deg, N_EDGES);
    scan_part_kernel<<<SCAN_NB, 256, 0, stream>>>(deg, bsum, dhist, N_NODES);
    scan_top_kernel<<<1, 256, 0, stream>>>(bsum, bbase, dhist, dcur);
    scan_write_perm_kernel<<<SCAN_NB, 256, 0, stream>>>(deg, bbase, rowptr, cursor, dcur, perm, N_NODES);
    scatter_kernel<<<(N_EDGES + 255) / 256, 256, 0, stream>>>(src, dst, cursor, csrc, N_EDGES);

    auto egrid = [](int npw) {
        int waves = (N_NODES + npw - 1) / npw;
        return (waves + 3) / 4;
    };

    // Layer 1: 128 -> 32 (dual-W)
    gemm2_kernel<128, 32, 64, 4><<<(N_NODES + 63) / 64, 256, 0, stream>>>(x, Wl1, Wr1, xl, xr, N_NODES);
    edge_kernel<32, true><<<egrid(4), 256, 0, stream>>>(xl, xr, a1, b1, rowptr, csrc, perm, hB, N_NODES);
    // Layer 2: 32 -> 64 (dual-W)
    gemm2_kernel<32, 64, 32, 4><<<(N_NODES + 31) / 32, 256, 0, stream>>>(hB, Wl2, Wr2, xl, xr, N_NODES);
    edge_kernel<64, true><<<egrid(2), 256, 0, stream>>>(xl, xr, a2, b2, rowptr, csrc, perm, hA, N_NODES);
    // Layer 3: 64 -> 128 (split-W: TR=64, RPT=8)
    { int tiles = (N_NODES + 63) / 64;
      gemm1w_kernel<64, 128, 64, 8><<<2 * tiles, 256, 0, stream>>>(hA, Wl3, Wr3, xl, xr, N_NODES); }
    edge_kernel<128, false><<<egrid(1), 256, 0, stream>>>(xl, xr, a3, b3, rowptr, csrc, perm, hB, N_NODES);

    pool_kernel<<<(N_NODES + POOL_CHUNK - 1) / POOL_CHUNK, 128, 0, stream>>>(hB, batch, pool, N_NODES);
    mlp1_kernel<<<N_GRAPHS * 4, 256, 0, stream>>>(pool, mw1, mb1, act1);
    mlp_mid_kernel<1024, 512><<<N_GRAPHS * 8, 256, 0, stream>>>(act1, mw2, mb2, act2);
    mlp_mid_kernel<512, 128><<<N_GRAPHS * 2, 256, 0, stream>>>(act2, mw3, mb3, act3);
    mlp45_kernel<<<N_GRAPHS, 128, 0, stream>>>(act3, mw4, mb4, mw5, mb5, (float*)d_out);
}

// Round 13
// 463.576 us; speedup vs baseline: 1.0129x; 1.0129x over previous
//
#include <hip/hip_runtime.h>
#include <cfloat>

#define N_NODES 50000
#define N_EDGES 800000
#define N_GRAPHS 64
#define POOL_CHUNK 64
#define DEG_BUCKETS 64
#define SCAN_NB ((N_NODES + 255) / 256)   // 196

// ---------------- CSR build ----------------

__global__ void hist_kernel(const int* __restrict__ dst, int* __restrict__ deg, int n) {
    int i = blockIdx.x * blockDim.x + threadIdx.x;
    if (i < n) atomicAdd(&deg[dst[i]], 1);
}

// ---- parallel exclusive scan of deg -> rowptr/cursor (+ fused degree histogram) ----

__global__ __launch_bounds__(256) void scan_part_kernel(const int* __restrict__ deg,
                                                        int* __restrict__ bsum,
                                                        int* __restrict__ dhist, int n) {
    __shared__ int ws[4];
    __shared__ int lh[DEG_BUCKETS];
    int t = threadIdx.x;
    if (t < DEG_BUCKETS) lh[t] = 0;
    __syncthreads();
    int i = blockIdx.x * 256 + t;
    int v = (i < n) ? deg[i] : 0;
    if (i < n) {
        int d = (v > DEG_BUCKETS - 1) ? DEG_BUCKETS - 1 : v;
        atomicAdd(&lh[d], 1);
    }
    int s = v;
    for (int m = 32; m >= 1; m >>= 1) s += __shfl_xor(s, m, 64);
    if ((t & 63) == 0) ws[t >> 6] = s;
    __syncthreads();
    if (t == 0) bsum[blockIdx.x] = ws[0] + ws[1] + ws[2] + ws[3];
    if (t < DEG_BUCKETS && lh[t]) atomicAdd(&dhist[t], lh[t]);
}

// block-count scan + degree-bucket scan fused (both tiny, single block)
__global__ __launch_bounds__(256) void scan_top_kernel(const int* __restrict__ bsum,
                                                       int* __restrict__ bbase,
                                                       const int* __restrict__ dhist,
                                                       int* __restrict__ dcur) {
    __shared__ int sm[256];
    int t = threadIdx.x;
    int v = (t < SCAN_NB) ? bsum[t] : 0;
    sm[t] = v;
    __syncthreads();
    for (int off = 1; off < 256; off <<= 1) {
        int x = (t >= off) ? sm[t - off] : 0;
        __syncthreads();
        sm[t] += x;
        __syncthreads();
    }
    bbase[t] = sm[t] - v;                       // exclusive
    if (t == 255) bbase[256] = sm[255];         // total
    if (t < 64) {
        int dv = dhist[t];
        int incl = dv;
        for (int off = 1; off < 64; off <<= 1) {
            int x = __shfl_up(incl, off, 64);
            if (t >= off) incl += x;
        }
        dcur[t] = incl - dv;                    // exclusive
    }
}

// fused: rowptr/cursor write + degree-bucket permutation scatter
__global__ __launch_bounds__(256) void scan_write_perm_kernel(const int* __restrict__ deg,
        const int* __restrict__ bbase, int* __restrict__ rowptr,
        int* __restrict__ cursor, int* __restrict__ dcur,
        int* __restrict__ perm, int n) {
    __shared__ int sm[256];
    __shared__ int lh[DEG_BUCKETS];
    __shared__ int lbase[DEG_BUCKETS];
    int t = threadIdx.x;
    int b = blockIdx.x;
    int i = b * 256 + t;
    int v = (i < n) ? deg[i] : 0;
    sm[t] = v;
    if (t < DEG_BUCKETS) lh[t] = 0;
    __syncthreads();
    int d = 0, loc = 0;
    bool valid = (i < n);
    if (valid) {
        d = (v > DEG_BUCKETS - 1) ? DEG_BUCKETS - 1 : v;
        loc = atomicAdd(&lh[d], 1);             // local rank within (block, bin)
    }
    for (int off = 1; off < 256; off <<= 1) {
        int x = (t >= off) ? sm[t - off] : 0;
        __syncthreads();
        sm[t] += x;
        __syncthreads();
    }
    if (t < DEG_BUCKETS)
        lbase[t] = lh[t] ? atomicAdd(&dcur[t], lh[t]) : 0;
    if (valid) {
        int e = bbase[b] + sm[t] - v;
        rowptr[i] = e;
        cursor[i] = e;
    }
    if (b == 0 && t == 0) rowptr[n] = bbase[256];
    __syncthreads();
    if (valid) perm[lbase[d] + loc] = i;
}

__global__ void scatter_kernel(const int* __restrict__ src, const int* __restrict__ dst,
                               int* __restrict__ cursor, int* __restrict__ csrc, int n) {
    int i = blockIdx.x * blockDim.x + threadIdx.x;
    if (i < n) {
        int d = dst[i];
        int p = atomicAdd(&cursor[d], 1);
        csrc[p] = src[i];
    }
}

// ---------------- fused dual GEMM: xl = h@Wl, xr = h@Wr ----------------
// One block per row-tile (non-persistent — persistent variant was pathological, r8).

template<int DIN, int DOUT, int TR, int RPT>
__global__ __launch_bounds__(256) void gemm2_kernel(const float* __restrict__ h,
        const float* __restrict__ Wl, const float* __restrict__ Wr,
        float* __restrict__ xl, float* __restrict__ xr, int n) {
    constexpr int CG = (2 * DOUT) / 4;
    constexpr int RG = 256 / CG;
    static_assert(RG * RPT == TR, "tile rows mismatch");
    static_assert(RPT % 4 == 0, "RPT multiple of 4");
    constexpr int TRP = TR + 4;
    __shared__ float sW[2 * DIN * DOUT];
    __shared__ float sX[DIN * TRP];
    int tid = threadIdx.x;
    for (int i = tid; i < DIN * DOUT; i += 256) {
        sW[i] = Wl[i];
        sW[DIN * DOUT + i] = Wr[i];
    }
    int r0 = blockIdx.x * TR;
    for (int i = tid; i < TR * DIN; i += 256) {
        int row = i / DIN, k = i % DIN;
        float v = (r0 + row < n) ? h[(r0 + row) * DIN + k] : 0.f;
        sX[k * TRP + row] = v;
    }
    __syncthreads();

    int cg = tid % CG, rg = tid / CG;
    int c = cg * 4;
    int sel = (c >= DOUT) ? 1 : 0;
    int cc = c - sel * DOUT;
    const float* wp = sW + sel * DIN * DOUT + cc;
    const float* xp = sX + rg * RPT;

    float acc[RPT][4] = {};
#pragma unroll 4
    for (int k = 0; k < DIN; ++k) {
        float4 wv = *(const float4*)(wp + k * DOUT);
        float wa[4] = {wv.x, wv.y, wv.z, wv.w};
        float xa[RPT];
#pragma unroll
        for (int rr = 0; rr < RPT; rr += 4) {
            float4 xv = *(const float4*)(xp + k * TRP + rr);
            xa[rr + 0] = xv.x; xa[rr + 1] = xv.y; xa[rr + 2] = xv.z; xa[rr + 3] = xv.w;
        }
#pragma unroll
        for (int r = 0; r < RPT; ++r)
#pragma unroll
            for (int q = 0; q < 4; ++q)
                acc[r][q] += xa[r] * wa[q];
    }

    float* obase = sel ? xr : xl;
#pragma unroll
    for (int r = 0; r < RPT; ++r) {
        int row = r0 + rg * RPT + r;
        if (row < n) {
            float4 o = make_float4(acc[r][0], acc[r][1], acc[r][2], acc[r][3]);
            *(float4*)(obase + row * DOUT + cc) = o;
        }
    }
}

// Split-W variant: each block computes ONE of {xl, xr} (sel = blockIdx&1).
template<int DIN, int DOUT, int TR, int RPT>
__global__ __launch_bounds__(256) void gemm1w_kernel(const float* __restrict__ h,
        const float* __restrict__ Wl, const float* __restrict__ Wr,
        float* __restrict__ xl, float* __restrict__ xr, int n) {
    constexpr int CG = DOUT / 4;
    constexpr int RG = 256 / CG;
    static_assert(RG * RPT == TR, "tile rows mismatch");
    static_assert(RPT % 4 == 0, "RPT multiple of 4");
    constexpr int TRP = TR + 4;
    __shared__ float sW[DIN * DOUT];
    __shared__ float sX[DIN * TRP];
    int tid = threadIdx.x;
    int sel = blockIdx.x & 1;
    const float* W = sel ? Wr : Wl;
    for (int i = tid; i < DIN * DOUT; i += 256) sW[i] = W[i];
    int r0 = (blockIdx.x >> 1) * TR;
    for (int i = tid; i < TR * DIN; i += 256) {
        int row = i / DIN, k = i % DIN;
        float v = (r0 + row < n) ? h[(r0 + row) * DIN + k] : 0.f;
        sX[k * TRP + row] = v;
    }
    __syncthreads();

    int cg = tid % CG, rg = tid / CG;
    int cc = cg * 4;
    const float* wp = sW + cc;
    const float* xp = sX + rg * RPT;

    float acc[RPT][4] = {};
#pragma unroll 4
    for (int k = 0; k < DIN; ++k) {
        float4 wv = *(const float4*)(wp + k * DOUT);
        float wa[4] = {wv.x, wv.y, wv.z, wv.w};
        float xa[RPT];
#pragma unroll
        for (int rr = 0; rr < RPT; rr += 4) {
            float4 xv = *(const float4*)(xp + k * TRP + rr);
            xa[rr + 0] = xv.x; xa[rr + 1] = xv.y; xa[rr + 2] = xv.z; xa[rr + 3] = xv.w;
        }
#pragma unroll
        for (int r = 0; r < RPT; ++r)
#pragma unroll
            for (int q = 0; q < 4; ++q)
                acc[r][q] += xa[r] * wa[q];
    }

    float* obase = sel ? xr : xl;
#pragma unroll
    for (int r = 0; r < RPT; ++r) {
        int row = r0 + rg * RPT + r;
        if (row < n) {
            float4 o = make_float4(acc[r][0], acc[r][1], acc[r][2], acc[r][3]);
            *(float4*)(obase + row * DOUT + cc) = o;
        }
    }
}

// ---------------- fused per-node GATv2 softmax-aggregate ----------------
// Single lane-group per node (r11 form — best measured), LPT order, U-batch
// template: U=16 for layers 1/2 (latency-bound, mean degree 16 -> 1 batch),
// U=8 for layer 3 (fill-bound; don't add register pressure).

template<int DOUT, int U, bool LEAKY>
__global__ __launch_bounds__(256) void edge_kernel(
        const float* __restrict__ xl, const float* __restrict__ xr,
        const float* __restrict__ avec, const float* __restrict__ bias,
        const int* __restrict__ rowptr, const int* __restrict__ csrc,
        const int* __restrict__ perm,
        float* __restrict__ out, int n) {
    constexpr int LANES = DOUT / 4;              // 8 / 16 / 32
    constexpr int NPW = 64 / LANES;              // nodes per wave
    int wid = (blockIdx.x * blockDim.x + threadIdx.x) >> 6;
    int lane = threadIdx.x & 63;
    int group = lane / LANES;
    int gl = lane % LANES;
    int gnode = wid * NPW + group;
    if (gnode >= n) return;
    int node = perm[n - 1 - gnode];              // descending degree (LPT)

    constexpr float L2E = 1.44269504f;
    float4 a0 = *(const float4*)(avec + 4 * gl);
    float4 a6, a4;
    a6.x = 0.6f * L2E * a0.x; a6.y = 0.6f * L2E * a0.y;
    a6.z = 0.6f * L2E * a0.z; a6.w = 0.6f * L2E * a0.w;
    a4.x = 0.4f * L2E * a0.x; a4.y = 0.4f * L2E * a0.y;
    a4.z = 0.4f * L2E * a0.z; a4.w = 0.4f * L2E * a0.w;

    int nbase = node * DOUT + 4 * gl;
    float4 xrv = *(const float4*)(xr + nbase);
    const float* xlg = xl + 4 * gl;

    float4 acc = make_float4(0.f, 0.f, 0.f, 0.f);
    float denom = 0.f;
    int e0 = rowptr[node], e1 = rowptr[node + 1];

    for (int p = e0; p < e1; p += U) {
        int sidx[U];
#pragma unroll
        for (int u = 0; u < U; ++u) {
            int q = p + u;
            sidx[u] = (q < e1) ? csrc[q] : -1;
        }
        float4 xlv[U];
        float part[U];
#pragma unroll
        for (int u = 0; u < U; ++u) {
            int s = (sidx[u] >= 0) ? sidx[u] : 0;
            xlv[u] = *(const float4*)(xlg + s * DOUT);
            float t0 = xlv[u].x + xrv.x;
            float t1 = xlv[u].y + xrv.y;
            float t2 = xlv[u].z + xrv.z;
            float t3 = xlv[u].w + xrv.w;
            float pu = a6.x * t0 + a4.x * fabsf(t0);
            pu += a6.y * t1 + a4.y * fabsf(t1);
            pu += a6.z * t2 + a4.z * fabsf(t2);
            pu += a6.w * t3 + a4.w * fabsf(t3);
            part[u] = pu;
        }
#pragma unroll
        for (int mask = LANES / 2; mask >= 1; mask >>= 1)
#pragma unroll
            for (int u = 0; u < U; ++u)
                part[u] += __shfl_xor(part[u], mask, 64);
#pragma unroll
        for (int u = 0; u < U; ++u) {
            float w = __builtin_exp2f(part[u]);   // v_exp_f32
            w = (sidx[u] >= 0) ? w : 0.f;
            denom += w;
            acc.x += w * xlv[u].x; acc.y += w * xlv[u].y;
            acc.z += w * xlv[u].z; acc.w += w * xlv[u].w;
        }
    }
    float inv = 1.f / (denom + 1e-16f);
    float4 bv = *(const float4*)(bias + 4 * gl);
    float4 o;
    o.x = acc.x * inv + bv.x; o.y = acc.y * inv + bv.y;
    o.z = acc.z * inv + bv.z; o.w = acc.w * inv + bv.w;
    if (LEAKY) {
        o.x = (o.x > 0.f) ? o.x : 0.01f * o.x;
        o.y = (o.y > 0.f) ? o.y : 0.01f * o.y;
        o.z = (o.z > 0.f) ? o.z : 0.01f * o.z;
        o.w = (o.w > 0.f) ? o.w : 0.01f * o.w;
    }
    *(float4*)(out + nbase) = o;
}

// ---------------- global max pool (node-parallel, atomicMax on encoded uint) ----------------

__device__ __forceinline__ unsigned int enc_f32(float f) {
    unsigned int b = __float_as_uint(f);
    return (b & 0x80000000u) ? ~b : (b | 0x80000000u);
}
__device__ __forceinline__ float dec_f32(unsigned int u) {
    unsigned int b = (u & 0x80000000u) ? (u ^ 0x80000000u) : ~u;
    return __uint_as_float(b);
}

__global__ __launch_bounds__(128) void pool_kernel(const float* __restrict__ h,
        const int* __restrict__ batch, unsigned int* __restrict__ gout, int n) {
    int c0 = blockIdx.x * POOL_CHUNK;
    if (c0 >= n) return;
    int end = c0 + POOL_CHUNK; if (end > n) end = n;
    int d = threadIdx.x;  // 128
    float run = -FLT_MAX;
    int gcur = batch[c0];
    for (int nn = c0; nn < end; ++nn) {
        int g = batch[nn];
        if (g != gcur) {                       // wave-uniform branch
            atomicMax(&gout[gcur * 128 + d], enc_f32(run));
            run = -FLT_MAX;
            gcur = g;
        }
        run = fmaxf(run, h[nn * 128 + d]);
    }
    atomicMax(&gout[gcur * 128 + d], enc_f32(run));
}

// ---------------- MLP head: column x k-split parallel kernels ----------------

__global__ __launch_bounds__(256) void mlp1_kernel(const unsigned int* __restrict__ gpool,
        const float* __restrict__ w1, const float* __restrict__ b1,
        float* __restrict__ act1) {
    __shared__ float A[128];
    int g = blockIdx.x >> 2, chunk = blockIdx.x & 3;
    int t = threadIdx.x;
    if (t < 128) A[t] = dec_f32(gpool[g * 128 + t]);
    __syncthreads();
    int c = chunk * 256 + t;
    float a0 = b1[c], a1 = 0.f;
#pragma unroll 4
    for (int k = 0; k < 128; k += 2) {
        a0 += A[k] * w1[k * 1024 + c];
        a1 += A[k + 1] * w1[(k + 1) * 1024 + c];
    }
    act1[g * 1024 + c] = fmaxf(a0 + a1, 0.f);
}

template<int DIN, int DOUT>
__global__ __launch_bounds__(256) void mlp_mid_kernel(const float* __restrict__ actin,
        const float* __restrict__ w, const float* __restrict__ b,
        float* __restrict__ actout) {
    constexpr int CHUNKS = DOUT / 64;
    constexpr int KQ = DIN / 4;                 // k per split
    __shared__ float A[DIN];
    __shared__ float partial[4][64];
    int g = blockIdx.x / CHUNKS, chunk = blockIdx.x % CHUNKS;
    int t = threadIdx.x;
    for (int i = t; i < DIN; i += 256) A[i] = actin[g * DIN + i];
    __syncthreads();
    int c = chunk * 64 + (t & 63);
    int q = t >> 6;
    const float* wp = w + c + (size_t)q * KQ * DOUT;
    const float* ap = A + q * KQ;
    float a0 = 0.f, a1 = 0.f;
#pragma unroll 4
    for (int k = 0; k < KQ; k += 2) {
        a0 += ap[k] * wp[k * DOUT];
        a1 += ap[k + 1] * wp[(k + 1) * DOUT];
    }
    partial[q][t & 63] = a0 + a1;
    __syncthreads();
    if (t < 64) {
        float s = partial[0][t] + partial[1][t] + partial[2][t] + partial[3][t] + b[c];
        actout[g * DOUT + chunk * 64 + t] = fmaxf(s, 0.f);
    }
}

__global__ __launch_bounds__(128) void mlp45_kernel(const float* __restrict__ act3,
        const float* __restrict__ w4, const float* __restrict__ b4,
        const float* __restrict__ w5, const float* __restrict__ b5,
        float* __restrict__ out) {
    __shared__ float C[128], D[32];
    int g = blockIdx.x, t = threadIdx.x;
    if (t < 128) C[t] = act3[g * 128 + t];
    __syncthreads();
    if (t < 32) {
        float acc = b4[t];
#pragma unroll 4
        for (int k = 0; k < 128; ++k) acc += C[k] * w4[k * 32 + t];
        D[t] = fmaxf(acc, 0.f);
    }
    __syncthreads();
    if (t < 4) {
        float acc = b5[t];
#pragma unroll
        for (int k = 0; k < 32; ++k) acc += D[k] * w5[k * 4 + t];
        out[g * 4 + t] = acc;
    }
}

// ---------------- host launch ----------------

extern "C" void kernel_launch(void* const* d_in, const int* in_sizes, int n_in,
                              void* d_out, int out_size, void* d_ws, size_t ws_size,
                              hipStream_t stream) {
    const float* x     = (const float*)d_in[0];
    const int*   ei    = (const int*)d_in[1];
    const int*   batch = (const int*)d_in[2];
    const int*   src   = ei;
    const int*   dst   = ei + N_EDGES;
    const float* Wl1 = (const float*)d_in[3];
    const float* Wr1 = (const float*)d_in[4];
    const float* a1  = (const float*)d_in[5];
    const float* b1  = (const float*)d_in[6];
    const float* Wl2 = (const float*)d_in[7];
    const float* Wr2 = (const float*)d_in[8];
    const float* a2  = (const float*)d_in[9];
    const float* b2  = (const float*)d_in[10];
    const float* Wl3 = (const float*)d_in[11];
    const float* Wr3 = (const float*)d_in[12];
    const float* a3  = (const float*)d_in[13];
    const float* b3  = (const float*)d_in[14];
    const float* mw1 = (const float*)d_in[15];
    const float* mb1 = (const float*)d_in[16];
    const float* mw2 = (const float*)d_in[17];
    const float* mb2 = (const float*)d_in[18];
    const float* mw3 = (const float*)d_in[19];
    const float* mb3 = (const float*)d_in[20];
    const float* mw4 = (const float*)d_in[21];
    const float* mb4 = (const float*)d_in[22];
    const float* mw5 = (const float*)d_in[23];
    const float* mb5 = (const float*)d_in[24];

    char* ws = (char*)d_ws;
    size_t off = 0;
    auto alloc = [&](size_t bytes) -> void* {
        void* p = ws + off;
        off = (off + bytes + 255) & ~(size_t)255;
        return p;
    };
    // zero-init region: deg, dhist, pool contiguous -> single memset
    int*   deg    = (int*)alloc(N_NODES * 4);
    int*   dhist  = (int*)alloc(DEG_BUCKETS * 4);
    unsigned int* pool = (unsigned int*)alloc(N_GRAPHS * 128 * 4);
    size_t zero_bytes = off;   // covers deg..pool (0 == encoded -inf for pool)
    int*   rowptr = (int*)alloc((N_NODES + 1) * 4);
    int*   cursor = (int*)alloc(N_NODES * 4);
    int*   csrc   = (int*)alloc(N_EDGES * 4);
    float* xl     = (float*)alloc((size_t)N_NODES * 128 * 4);
    float* xr     = (float*)alloc((size_t)N_NODES * 128 * 4);
    float* hA     = (float*)alloc((size_t)N_NODES * 128 * 4);
    float* hB     = (float*)alloc((size_t)N_NODES * 128 * 4);
    int*   dcur   = (int*)alloc(DEG_BUCKETS * 4);
    int*   perm   = (int*)alloc(N_NODES * 4);
    int*   bsum   = (int*)alloc(SCAN_NB * 4);
    int*   bbase  = (int*)alloc(257 * 4);
    float* act1   = (float*)alloc(N_GRAPHS * 1024 * 4);
    float* act2   = (float*)alloc(N_GRAPHS * 512 * 4);
    float* act3   = (float*)alloc(N_GRAPHS * 128 * 4);

    hipMemsetAsync(deg, 0, zero_bytes, stream);
    hist_kernel<<<(N_EDGES + 255) / 256, 256, 0, stream>>>(dst, deg, N_EDGES);
    scan_part_kernel<<<SCAN_NB, 256, 0, stream>>>(deg, bsum, dhist, N_NODES);
    scan_top_kernel<<<1, 256, 0, stream>>>(bsum, bbase, dhist, dcur);
    scan_write_perm_kernel<<<SCAN_NB, 256, 0, stream>>>(deg, bbase, rowptr, cursor, dcur, perm, N_NODES);
    scatter_kernel<<<(N_EDGES + 255) / 256, 256, 0, stream>>>(src, dst, cursor, csrc, N_EDGES);

    auto egrid = [](int npw) {
        int waves = (N_NODES + npw - 1) / npw;
        return (waves + 3) / 4;
    };

    // Layer 1: 128 -> 32 (dual-W); U=16: mean degree 16 -> one batch
    gemm2_kernel<128, 32, 64, 4><<<(N_NODES + 63) / 64, 256, 0, stream>>>(x, Wl1, Wr1, xl, xr, N_NODES);
    edge_kernel<32, 16, true><<<egrid(8), 256, 0, stream>>>(xl, xr, a1, b1, rowptr, csrc, perm, hB, N_NODES);
    // Layer 2: 32 -> 64 (dual-W); U=16
    gemm2_kernel<32, 64, 32, 4><<<(N_NODES + 31) / 32, 256, 0, stream>>>(hB, Wl2, Wr2, xl, xr, N_NODES);
    edge_kernel<64, 16, true><<<egrid(4), 256, 0, stream>>>(xl, xr, a2, b2, rowptr, csrc, perm, hA, N_NODES);
    // Layer 3: 64 -> 128 (split-W gemm; U=8 — fill-bound, keep registers lean)
    { int tiles = (N_NODES + 63) / 64;
      gemm1w_kernel<64, 128, 64, 8><<<2 * tiles, 256, 0, stream>>>(hA, Wl3, Wr3, xl, xr, N_NODES); }
    edge_kernel<128, 8, false><<<egrid(2), 256, 0, stream>>>(xl, xr, a3, b3, rowptr, csrc, perm, hB, N_NODES);

    pool_kernel<<<(N_NODES + POOL_CHUNK - 1) / POOL_CHUNK, 128, 0, stream>>>(hB, batch, pool, N_NODES);
    mlp1_kernel<<<N_GRAPHS * 4, 256, 0, stream>>>(pool, mw1, mb1, act1);
    mlp_mid_kernel<1024, 512><<<N_GRAPHS * 8, 256, 0, stream>>>(act1, mw2, mb2, act2);
    mlp_mid_kernel<512, 128><<<N_GRAPHS * 2, 256, 0, stream>>>(act2, mw3, mb3, act3);
    mlp45_kernel<<<N_GRAPHS, 128, 0, stream>>>(act3, mw4, mb4, mw5, mb5, (float*)d_out);
}